// Round 1
// baseline (387.926 us; speedup 1.0000x reference)
//
#include <hip/hip_runtime.h>
#include <stdint.h>
#include <stddef.h>

#define T_STEPS 28
#define I_DIM 28
#define H_DIM 64
#define O_DIM 10
#define BT 64   // batch rows per block

typedef short bf16x8 __attribute__((ext_vector_type(8)));
typedef float f32x4  __attribute__((ext_vector_type(4)));

__device__ __forceinline__ short f2bf(float f){
    uint32_t u = __builtin_bit_cast(uint32_t, f);
    u = (u + 0x7fffu + ((u >> 16) & 1u)) >> 16;
    return (short)u;
}
__device__ __forceinline__ float sigmoid_fast(float x){
    return __builtin_amdgcn_rcpf(1.0f + __builtin_amdgcn_exp2f(-1.4426950408889634f * x));
}
__device__ __forceinline__ float tanh_fast(float x){
    return 1.0f - 2.0f * __builtin_amdgcn_rcpf(1.0f + __builtin_amdgcn_exp2f(2.8853900817779268f * x));
}

__global__ __launch_bounds__(256, 3)
void lstm_fused(const float* __restrict__ x,
                const float* __restrict__ W_ih,
                const float* __restrict__ W_hh,
                const float* __restrict__ b_ih,
                const float* __restrict__ b_hh,
                const float* __restrict__ W_out,
                const float* __restrict__ b_out,
                float* __restrict__ out)
{
    // LDS
    __shared__ short x_lds[64][40];   // bf16 x tile, K padded 28->32 (cols 28..31 zero), stride 40 for banks/align
    __shared__ short h_lds[64][72];   // bf16 h state, stride 72 -> 144B rows, 16B-aligned frag reads
    __shared__ float hf[64][65];      // final h in fp32 for output projection
    __shared__ float wout_t[H_DIM * O_DIM]; // transposed W_out: [j][o]
    __shared__ float bout_s[O_DIM];

    const int tid  = threadIdx.x;
    const int w    = tid >> 6;     // wave id 0..3 -> owns hidden cols [16w,16w+16)
    const int lane = tid & 63;
    const int col  = lane & 15;
    const int quad = lane >> 4;
    const int b0   = blockIdx.x * BT;

    // ---- load weight B-fragments into registers (once) ----
    // B[k][n] layout: lane holds n = 16*tile + (lane&15), k = quad*8 + j
    bf16x8 wih[4];
    bf16x8 whh[2][4];
    float  bias_v[4];
    #pragma unroll
    for (int nt = 0; nt < 4; ++nt){
        const int n = nt * 64 + w * 16 + col;   // global gate column; gate type = nt (i,f,g,o)
        #pragma unroll
        for (int j = 0; j < 8; ++j){
            const int k = quad * 8 + j;
            wih[nt][j] = (k < I_DIM) ? f2bf(W_ih[n * I_DIM + k]) : (short)0;
        }
        #pragma unroll
        for (int s = 0; s < 2; ++s)
            #pragma unroll
            for (int j = 0; j < 8; ++j){
                const int k = s * 32 + quad * 8 + j;
                whh[s][nt][j] = f2bf(W_hh[n * H_DIM + k]);
            }
        bias_v[nt] = b_ih[n] + b_hh[n];
    }

    // ---- stage W_out (transposed) + b_out ----
    for (int idx = tid; idx < H_DIM * O_DIM; idx += 256){
        const int j = idx / O_DIM;
        const int o = idx - j * O_DIM;
        wout_t[idx] = W_out[o * H_DIM + j];
    }
    if (tid < O_DIM) bout_s[tid] = b_out[tid];

    // ---- zero h state and x pad columns ----
    for (int idx = tid; idx < 64 * 72; idx += 256) (&h_lds[0][0])[idx] = 0;
    for (int idx = tid; idx < 64 * 12; idx += 256){
        const int r = idx / 12;
        x_lds[r][28 + (idx - r * 12)] = 0;
    }

    // ---- x staging mapping: 4 threads per row, 7 floats each ----
    const int row = tid >> 2;
    const int seg = tid & 3;
    const float* px = x + (size_t)(b0 + row) * (T_STEPS * I_DIM) + seg * 7;

    float xa[7];
    #pragma unroll
    for (int u = 0; u < 7; ++u) xa[u] = px[u];   // prefetch t=0

    float cst[4][4];
    #pragma unroll
    for (int mt = 0; mt < 4; ++mt)
        #pragma unroll
        for (int r = 0; r < 4; ++r) cst[mt][r] = 0.0f;

    for (int t = 0; t < T_STEPS; ++t){
        // stage x(t) into LDS (bf16)
        #pragma unroll
        for (int u = 0; u < 7; ++u) x_lds[row][seg * 7 + u] = f2bf(xa[u]);
        // prefetch x(t+1) -> latency overlaps with MFMA + activations
        if (t < T_STEPS - 1){
            #pragma unroll
            for (int u = 0; u < 7; ++u) xa[u] = px[(t + 1) * I_DIM + u];
        }
        __syncthreads();   // B1: x_lds ready, h_lds(t-1) writes done

        // init accumulators with bias (bias depends only on n = column)
        f32x4 acc[4][4];
        #pragma unroll
        for (int mt = 0; mt < 4; ++mt)
            #pragma unroll
            for (int nt = 0; nt < 4; ++nt){
                f32x4 c4;
                c4[0] = bias_v[nt]; c4[1] = bias_v[nt]; c4[2] = bias_v[nt]; c4[3] = bias_v[nt];
                acc[mt][nt] = c4;
            }

        // x-projection: [64 x 32] @ [32 x 256]
        #pragma unroll
        for (int mt = 0; mt < 4; ++mt){
            bf16x8 a = *(const bf16x8*)&x_lds[mt * 16 + col][quad * 8];
            #pragma unroll
            for (int nt = 0; nt < 4; ++nt)
                acc[mt][nt] = __builtin_amdgcn_mfma_f32_16x16x32_bf16(a, wih[nt], acc[mt][nt], 0, 0, 0);
        }
        // recurrence: [64 x 64] @ [64 x 256]
        #pragma unroll
        for (int s = 0; s < 2; ++s)
            #pragma unroll
            for (int mt = 0; mt < 4; ++mt){
                bf16x8 a = *(const bf16x8*)&h_lds[mt * 16 + col][s * 32 + quad * 8];
                #pragma unroll
                for (int nt = 0; nt < 4; ++nt)
                    acc[mt][nt] = __builtin_amdgcn_mfma_f32_16x16x32_bf16(a, whh[s][nt], acc[mt][nt], 0, 0, 0);
            }

        // activations + cell update (all in registers; D-layout: row = quad*4+r, col-lane owns j = 16w+col)
        float hv[4][4];
        #pragma unroll
        for (int mt = 0; mt < 4; ++mt){
            #pragma unroll
            for (int r = 0; r < 4; ++r){
                const float gi = sigmoid_fast(acc[mt][0][r]);
                const float gf = sigmoid_fast(acc[mt][1][r]);
                const float gg = tanh_fast  (acc[mt][2][r]);
                const float go = sigmoid_fast(acc[mt][3][r]);
                const float c_ = gf * cst[mt][r] + gi * gg;
                cst[mt][r] = c_;
                hv[mt][r] = go * tanh_fast(c_);
            }
        }
        __syncthreads();   // B2: all h_lds reads of this step done

        if (t != T_STEPS - 1){
            #pragma unroll
            for (int mt = 0; mt < 4; ++mt)
                #pragma unroll
                for (int r = 0; r < 4; ++r)
                    h_lds[mt * 16 + quad * 4 + r][w * 16 + col] = f2bf(hv[mt][r]);
        } else {
            #pragma unroll
            for (int mt = 0; mt < 4; ++mt)
                #pragma unroll
                for (int r = 0; r < 4; ++r)
                    hf[mt * 16 + quad * 4 + r][w * 16 + col] = hv[mt][r];
        }
    }
    __syncthreads();

    // ---- output projection: out[m][o] = sum_j hf[m][j] * W_out[o][j] + b_out[o] ----
    for (int idx = tid; idx < BT * O_DIM; idx += 256){
        const int m = idx / O_DIM;
        const int o = idx - m * O_DIM;
        float s = bout_s[o];
        #pragma unroll 8
        for (int j = 0; j < H_DIM; ++j)
            s += hf[m][j] * wout_t[j * O_DIM + o];
        out[(size_t)b0 * O_DIM + idx] = s;
    }
}

extern "C" void kernel_launch(void* const* d_in, const int* in_sizes, int n_in,
                              void* d_out, int out_size, void* d_ws, size_t ws_size,
                              hipStream_t stream) {
    const float* x     = (const float*)d_in[0];
    const float* W_ih  = (const float*)d_in[1];
    const float* W_hh  = (const float*)d_in[2];
    const float* b_ih  = (const float*)d_in[3];
    const float* b_hh  = (const float*)d_in[4];
    const float* W_out = (const float*)d_in[5];
    const float* b_out = (const float*)d_in[6];
    float* out = (float*)d_out;

    const int grid = 65536 / BT;   // 1024 blocks
    lstm_fused<<<grid, 256, 0, stream>>>(x, W_ih, W_hh, b_ih, b_hh, W_out, b_out, out);
}